// Round 1
// baseline (2718.182 us; speedup 1.0000x reference)
//
#include <hip/hip_runtime.h>
#include <hip/hip_bf16.h>
#include <cstdint>
#include <cstddef>

// MoE (Mixtral-style) top-2-of-8, T=8192, H=2048, I=4096, fp32 in/out.
// Strategy: route -> compact bf16 gather -> grouped bf16-MFMA GEMMs
// (fp32 weights converted to bf16 during LDS staging), h kept bf16 in ws,
// out accumulated with fp32 atomics. Requires ws_size >= ~200 MB.

#define NTOK 8192
#define HID 2048
#define INTER 4096
#define NEXP 8

typedef __attribute__((ext_vector_type(4))) float f32x4;
typedef __attribute__((ext_vector_type(8))) short bf16x8;
typedef unsigned short u16;
typedef unsigned int u32;

// ---- workspace layout (bytes) ----
static constexpr size_t O_CNT  = 0;      // 8 int   expert counters
static constexpr size_t O_NTL  = 32;     // 1 int   #tiles
static constexpr size_t O_BASE = 64;     // 9 int   exclusive prefix of counts
static constexpr size_t O_TE   = 128;    // 160 int tile -> expert
static constexpr size_t O_TM   = 768;    // 160 int tile -> m0
static constexpr size_t O_TOK  = 4096;                            // 8*8192 int
static constexpr size_t O_WGT  = O_TOK + (size_t)NEXP * NTOK * 4; // 8*8192 f32
static constexpr size_t O_XG   = (size_t)1 << 20;                 // gathered x, bf16, (16384+256) x 2048
static constexpr size_t O_H    = O_XG + (size_t)(2 * NTOK + 256) * HID * 2; // h, bf16, (16384+256) x 4096

__device__ __forceinline__ u16 f2bf(float f) {
  union { float f; u32 u; } c; c.f = f;
  u32 r = c.u + 0x7fffu + ((c.u >> 16) & 1u);   // round-to-nearest-even
  return (u16)(r >> 16);
}

__device__ __forceinline__ bf16x8 pack8(float4 a, float4 b) {
  bf16x8 r;
  r[0] = (short)f2bf(a.x); r[1] = (short)f2bf(a.y);
  r[2] = (short)f2bf(a.z); r[3] = (short)f2bf(a.w);
  r[4] = (short)f2bf(b.x); r[5] = (short)f2bf(b.y);
  r[6] = (short)f2bf(b.z); r[7] = (short)f2bf(b.w);
  return r;
}

// ---------------- router: logits -> top2 -> renorm weights -> expert lists ----------------
__global__ __launch_bounds__(256) void k_router(
    const float* __restrict__ x, const float* __restrict__ gate,
    const int* __restrict__ index, int* __restrict__ cnt,
    int* __restrict__ tokid, float* __restrict__ wgt)
{
  const int wave = threadIdx.x >> 6, lane = threadIdx.x & 63;
  const int t = blockIdx.x * 4 + wave;
  const float* g = gate + (size_t)index[0] * NEXP * HID;
  const float* xr = x + (size_t)t * HID;
  float acc[NEXP];
  #pragma unroll
  for (int e = 0; e < NEXP; ++e) acc[e] = 0.f;
  for (int hh = lane; hh < HID; hh += 64) {
    const float xv = xr[hh];
    #pragma unroll
    for (int e = 0; e < NEXP; ++e) acc[e] += xv * g[e * HID + hh];
  }
  #pragma unroll
  for (int off = 32; off > 0; off >>= 1) {
    #pragma unroll
    for (int e = 0; e < NEXP; ++e) acc[e] += __shfl_xor(acc[e], off);
  }
  if (lane == 0) {
    int i0 = 0; float v0 = acc[0];
    #pragma unroll
    for (int e = 1; e < NEXP; ++e) if (acc[e] > v0) { v0 = acc[e]; i0 = e; }
    int i1 = -1; float v1 = -3.4e38f;
    #pragma unroll
    for (int e = 0; e < NEXP; ++e) if (e != i0 && acc[e] > v1) { v1 = acc[e]; i1 = e; }
    // renormalized top-2 softmax weights: e^{v0}/(e^{v0}+e^{v1})
    const float w0 = 1.f / (1.f + expf(v1 - v0));
    const int p0 = atomicAdd(&cnt[i0], 1);
    tokid[i0 * NTOK + p0] = t; wgt[i0 * NTOK + p0] = w0;
    const int p1 = atomicAdd(&cnt[i1], 1);
    tokid[i1 * NTOK + p1] = t; wgt[i1 * NTOK + p1] = 1.f - w0;
  }
}

// ---------------- prefix: bases + flattened (expert, m0) tile table ----------------
__global__ void k_prefix(const int* __restrict__ cnt, int* __restrict__ base,
                         int* __restrict__ te, int* __restrict__ tm,
                         int* __restrict__ ntl)
{
  if (threadIdx.x == 0 && blockIdx.x == 0) {
    int b = 0, n = 0;
    for (int e = 0; e < NEXP; ++e) {
      base[e] = b;
      for (int m0 = 0; m0 < cnt[e]; m0 += 128) { te[n] = e; tm[n] = m0; ++n; }
      b += cnt[e];
    }
    base[NEXP] = b;
    *ntl = n;
  }
}

// ---------------- gather: compact per-expert token rows, fp32 -> bf16 ----------------
__global__ __launch_bounds__(256) void k_gather(
    const float* __restrict__ x, const int* __restrict__ base,
    const int* __restrict__ tokid, u16* __restrict__ xg)
{
  const int s = blockIdx.x;           // slot 0..16383
  int e = 0;
  #pragma unroll
  for (int i = 1; i < NEXP; ++i) if (s >= base[i]) e = i;
  const int t = tokid[e * NTOK + (s - base[e])];
  const float4* src = (const float4*)(x + (size_t)t * HID);
  const float4 a = src[threadIdx.x * 2];
  const float4 b = src[threadIdx.x * 2 + 1];
  *(bf16x8*)(xg + (size_t)s * HID + threadIdx.x * 8) = pack8(a, b);
}

// ---------------- ffn1: h = silu(x@w1^T) * (x@w3^T), grouped, tile 128x64 ----------------
// Block: 256 thr = 4 waves (wr = m-half, wc: 0 -> w1 cols, 1 -> w3 cols).
// B-tile rows [0,64) = w1[n0..n0+64), rows [64,128) = w3[n0..n0+64).
__global__ __launch_bounds__(256, 2) void k_ffn1(
    const u16* __restrict__ xg, const float* __restrict__ w1,
    const float* __restrict__ w3, const int* __restrict__ index,
    const int* __restrict__ cnt, const int* __restrict__ base,
    const int* __restrict__ te, const int* __restrict__ tm,
    const int* __restrict__ ntl, u16* __restrict__ h)
{
  if ((int)blockIdx.y >= *ntl) return;
  const int e  = te[blockIdx.y];
  const int m0 = tm[blockIdx.y];
  const int n0 = blockIdx.x * 64;
  const int cn = cnt[e];
  const int b0 = base[e];
  const size_t loff = (size_t)index[0] * NEXP * (size_t)INTER * HID;

  const int tid = threadIdx.x, lane = tid & 63, w = tid >> 6;
  const int wr = w >> 1, wc = w & 1;

  __shared__ __align__(16) short SM[4][128 * 32];   // A: SM[0],SM[1]; B: SM[2],SM[3]

  const int srow = tid >> 1;            // staged row 0..127
  const int g0 = (tid & 1) * 2;         // 16B-chunk pair
  const u16* asrc = xg + (size_t)(b0 + m0 + srow) * HID + g0 * 8;
  const float* bsrc = (srow < 64)
      ? (w1 + loff + ((size_t)e * INTER + n0 + srow) * HID + g0 * 8)
      : (w3 + loff + ((size_t)e * INTER + n0 + srow - 64) * HID + g0 * 8);

  f32x4 acc[4][4];
  #pragma unroll
  for (int i = 0; i < 4; ++i)
    #pragma unroll
    for (int j = 0; j < 4; ++j) acc[i][j] = (f32x4)0.f;

  constexpr int NK = HID / 32;

  { // prologue: stage k=0 into buf 0
    const bf16x8 a0 = *(const bf16x8*)(asrc);
    const bf16x8 a1 = *(const bf16x8*)(asrc + 8);
    const float4 f0 = *(const float4*)(bsrc);
    const float4 f1 = *(const float4*)(bsrc + 4);
    const float4 f2 = *(const float4*)(bsrc + 8);
    const float4 f3 = *(const float4*)(bsrc + 12);
    *(bf16x8*)&SM[0][(srow * 4 + g0) * 8] = a0;
    *(bf16x8*)&SM[0][(srow * 4 + g0 + 1) * 8] = a1;
    *(bf16x8*)&SM[2][(srow * 4 + g0) * 8] = pack8(f0, f1);
    *(bf16x8*)&SM[2][(srow * 4 + g0 + 1) * 8] = pack8(f2, f3);
  }
  __syncthreads();

  int buf = 0;
  for (int kt = 0; kt < NK; ++kt) {
    bf16x8 a0, a1; float4 f0, f1, f2, f3;
    const bool pf = (kt + 1 < NK);
    if (pf) {
      const int ko = (kt + 1) * 32;
      a0 = *(const bf16x8*)(asrc + ko);
      a1 = *(const bf16x8*)(asrc + ko + 8);
      f0 = *(const float4*)(bsrc + ko);
      f1 = *(const float4*)(bsrc + ko + 4);
      f2 = *(const float4*)(bsrc + ko + 8);
      f3 = *(const float4*)(bsrc + ko + 12);
    }
    bf16x8 af[4], bfr[4];
    const int kg = lane >> 4;
    #pragma unroll
    for (int i = 0; i < 4; ++i) {
      const int ar = wr * 64 + i * 16 + (lane & 15);
      const int br = wc * 64 + i * 16 + (lane & 15);
      af[i]  = *(const bf16x8*)&SM[buf][(ar * 4 + kg) * 8];
      bfr[i] = *(const bf16x8*)&SM[2 + buf][(br * 4 + kg) * 8];
    }
    #pragma unroll
    for (int i = 0; i < 4; ++i)
      #pragma unroll
      for (int j = 0; j < 4; ++j)
        acc[i][j] = __builtin_amdgcn_mfma_f32_16x16x32_bf16(af[i], bfr[j], acc[i][j], 0, 0, 0);
    if (pf) {
      *(bf16x8*)&SM[buf ^ 1][(srow * 4 + g0) * 8] = a0;
      *(bf16x8*)&SM[buf ^ 1][(srow * 4 + g0 + 1) * 8] = a1;
      *(bf16x8*)&SM[3 - buf][(srow * 4 + g0) * 8] = pack8(f0, f1);
      *(bf16x8*)&SM[3 - buf][(srow * 4 + g0 + 1) * 8] = pack8(f2, f3);
    }
    __syncthreads();
    buf ^= 1;
  }

  // epilogue: wc==1 waves publish h3, wc==0 waves combine + store bf16 h
  float* h3x = (float*)&SM[0][0];     // 128 x 64 f32 = 32 KB (reuse staging LDS)
  if (wc == 1) {
    #pragma unroll
    for (int i = 0; i < 4; ++i)
      #pragma unroll
      for (int j = 0; j < 4; ++j)
        #pragma unroll
        for (int r = 0; r < 4; ++r) {
          const int ml = wr * 64 + i * 16 + (lane >> 4) * 4 + r;
          const int nl = j * 16 + (lane & 15);
          h3x[ml * 64 + nl] = acc[i][j][r];
        }
  }
  __syncthreads();
  if (wc == 0) {
    #pragma unroll
    for (int i = 0; i < 4; ++i) {
      #pragma unroll
      for (int r = 0; r < 4; ++r) {
        const int ml = wr * 64 + i * 16 + (lane >> 4) * 4 + r;
        const int m = m0 + ml;
        if (m < cn) {
          #pragma unroll
          for (int j = 0; j < 4; ++j) {
            const int nl = j * 16 + (lane & 15);
            const float h1v = acc[i][j][r];
            const float hv = h3x[ml * 64 + nl] * h1v / (1.f + expf(-h1v));
            h[(size_t)(b0 + m) * INTER + n0 + nl] = f2bf(hv);
          }
        }
      }
    }
  }
}

// ---------------- ffn2: out[tok] += wgt * (h @ w2^T), grouped, tile 128x128 ----------------
__global__ __launch_bounds__(256, 2) void k_ffn2(
    const u16* __restrict__ h, const float* __restrict__ w2,
    const int* __restrict__ index, const int* __restrict__ cnt,
    const int* __restrict__ base, const int* __restrict__ te,
    const int* __restrict__ tm, const int* __restrict__ ntl,
    const int* __restrict__ tokid, const float* __restrict__ wgt,
    float* __restrict__ out)
{
  if ((int)blockIdx.y >= *ntl) return;
  const int e  = te[blockIdx.y];
  const int m0 = tm[blockIdx.y];
  const int n0 = blockIdx.x * 128;
  const int cn = cnt[e];
  const int b0 = base[e];
  const size_t loff = (size_t)index[0] * NEXP * (size_t)HID * INTER;

  const int tid = threadIdx.x, lane = tid & 63, w = tid >> 6;
  const int wr = w >> 1, wc = w & 1;

  __shared__ __align__(16) short SM[4][128 * 32];

  const int srow = tid >> 1;
  const int g0 = (tid & 1) * 2;
  const u16* asrc = h + (size_t)(b0 + m0 + srow) * INTER + g0 * 8;
  const float* bsrc = w2 + loff + ((size_t)e * HID + n0 + srow) * INTER + g0 * 8;

  f32x4 acc[4][4];
  #pragma unroll
  for (int i = 0; i < 4; ++i)
    #pragma unroll
    for (int j = 0; j < 4; ++j) acc[i][j] = (f32x4)0.f;

  constexpr int NK = INTER / 32;

  {
    const bf16x8 a0 = *(const bf16x8*)(asrc);
    const bf16x8 a1 = *(const bf16x8*)(asrc + 8);
    const float4 f0 = *(const float4*)(bsrc);
    const float4 f1 = *(const float4*)(bsrc + 4);
    const float4 f2 = *(const float4*)(bsrc + 8);
    const float4 f3 = *(const float4*)(bsrc + 12);
    *(bf16x8*)&SM[0][(srow * 4 + g0) * 8] = a0;
    *(bf16x8*)&SM[0][(srow * 4 + g0 + 1) * 8] = a1;
    *(bf16x8*)&SM[2][(srow * 4 + g0) * 8] = pack8(f0, f1);
    *(bf16x8*)&SM[2][(srow * 4 + g0 + 1) * 8] = pack8(f2, f3);
  }
  __syncthreads();

  int buf = 0;
  for (int kt = 0; kt < NK; ++kt) {
    bf16x8 a0, a1; float4 f0, f1, f2, f3;
    const bool pf = (kt + 1 < NK);
    if (pf) {
      const int ko = (kt + 1) * 32;
      a0 = *(const bf16x8*)(asrc + ko);
      a1 = *(const bf16x8*)(asrc + ko + 8);
      f0 = *(const float4*)(bsrc + ko);
      f1 = *(const float4*)(bsrc + ko + 4);
      f2 = *(const float4*)(bsrc + ko + 8);
      f3 = *(const float4*)(bsrc + ko + 12);
    }
    bf16x8 af[4], bfr[4];
    const int kg = lane >> 4;
    #pragma unroll
    for (int i = 0; i < 4; ++i) {
      const int ar = wr * 64 + i * 16 + (lane & 15);
      const int br = wc * 64 + i * 16 + (lane & 15);
      af[i]  = *(const bf16x8*)&SM[buf][(ar * 4 + kg) * 8];
      bfr[i] = *(const bf16x8*)&SM[2 + buf][(br * 4 + kg) * 8];
    }
    #pragma unroll
    for (int i = 0; i < 4; ++i)
      #pragma unroll
      for (int j = 0; j < 4; ++j)
        acc[i][j] = __builtin_amdgcn_mfma_f32_16x16x32_bf16(af[i], bfr[j], acc[i][j], 0, 0, 0);
    if (pf) {
      *(bf16x8*)&SM[buf ^ 1][(srow * 4 + g0) * 8] = a0;
      *(bf16x8*)&SM[buf ^ 1][(srow * 4 + g0 + 1) * 8] = a1;
      *(bf16x8*)&SM[3 - buf][(srow * 4 + g0) * 8] = pack8(f0, f1);
      *(bf16x8*)&SM[3 - buf][(srow * 4 + g0 + 1) * 8] = pack8(f2, f3);
    }
    __syncthreads();
    buf ^= 1;
  }

  #pragma unroll
  for (int i = 0; i < 4; ++i) {
    #pragma unroll
    for (int r = 0; r < 4; ++r) {
      const int ml = wr * 64 + i * 16 + (lane >> 4) * 4 + r;
      const int m = m0 + ml;
      if (m < cn) {
        const int t  = tokid[e * NTOK + m];
        const float wv = wgt[e * NTOK + m];
        #pragma unroll
        for (int j = 0; j < 4; ++j) {
          const int col = n0 + wc * 64 + j * 16 + (lane & 15);
          atomicAdd(&out[(size_t)t * HID + col], wv * acc[i][j][r]);
        }
      }
    }
  }
}

extern "C" void kernel_launch(void* const* d_in, const int* in_sizes, int n_in,
                              void* d_out, int out_size, void* d_ws, size_t ws_size,
                              hipStream_t stream)
{
  const int*   index = (const int*)d_in[0];
  const float* x     = (const float*)d_in[1];
  const float* gate  = (const float*)d_in[2];
  const float* w1    = (const float*)d_in[3];
  const float* w3    = (const float*)d_in[4];
  const float* w2    = (const float*)d_in[5];
  float* out = (float*)d_out;
  char*  ws  = (char*)d_ws;

  int*   cnt   = (int*)(ws + O_CNT);
  int*   ntl   = (int*)(ws + O_NTL);
  int*   basep = (int*)(ws + O_BASE);
  int*   te    = (int*)(ws + O_TE);
  int*   tm    = (int*)(ws + O_TM);
  int*   tokid = (int*)(ws + O_TOK);
  float* wgtp  = (float*)(ws + O_WGT);
  u16*   xg    = (u16*)(ws + O_XG);
  u16*   hbuf  = (u16*)(ws + O_H);

  hipMemsetAsync(ws, 0, 4096, stream);                                   // counters/tables
  hipMemsetAsync(d_out, 0, (size_t)NTOK * HID * sizeof(float), stream);  // atomic accumulate target

  k_router<<<NTOK / 4, 256, 0, stream>>>(x, gate, index, cnt, tokid, wgtp);
  k_prefix<<<1, 1, 0, stream>>>(cnt, basep, te, tm, ntl);
  k_gather<<<2 * NTOK, 256, 0, stream>>>(x, basep, tokid, xg);
  k_ffn1<<<dim3(INTER / 64, 160), 256, 0, stream>>>(xg, w1, w3, index, cnt, basep, te, tm, ntl, hbuf);
  k_ffn2<<<dim3(HID / 128, 160), 256, 0, stream>>>(hbuf, w2, index, cnt, basep, te, tm, ntl, tokid, wgtp, out);
}